// Round 1
// baseline (471.988 us; speedup 1.0000x reference)
//
#include <hip/hip_runtime.h>
#include <hip/hip_bf16.h>

// GCN: 3 layers over fixed graph (N=100000 nodes, E=1600000 edges).
// Strategy: build CSR (by dst) each call, then gather-only aggregations.

constexpr int SCAN_CHUNK = 1024;

__global__ void zero_i32(int* __restrict__ p, int n) {
    int i = blockIdx.x * blockDim.x + threadIdx.x;
    if (i < n) p[i] = 0;
}

__global__ void hist_kernel(const int* __restrict__ dst, int* __restrict__ deg, int n_edges) {
    int e = blockIdx.x * blockDim.x + threadIdx.x;
    if (e < n_edges) atomicAdd(&deg[dst[e]], 1);
}

// Per-chunk (1024 elems) exclusive scan; writes local-exclusive values + chunk totals.
__global__ __launch_bounds__(256) void scan1(const int* __restrict__ deg, int* __restrict__ rowptr,
                                             int* __restrict__ bsum, int n) {
    __shared__ int s[256];
    const int t = threadIdx.x;
    const int base = blockIdx.x * SCAN_CHUNK + t * 4;
    int v[4]; int ts = 0;
#pragma unroll
    for (int j = 0; j < 4; ++j) { int i = base + j; v[j] = (i < n) ? deg[i] : 0; ts += v[j]; }
    s[t] = ts; __syncthreads();
    for (int off = 1; off < 256; off <<= 1) {
        int x = (t >= off) ? s[t - off] : 0;
        __syncthreads();
        s[t] += x;
        __syncthreads();
    }
    int run = s[t] - ts;  // exclusive prefix of this thread's 4 elems (chunk-local)
#pragma unroll
    for (int j = 0; j < 4; ++j) { int i = base + j; if (i < n) rowptr[i] = run; run += v[j]; }
    if (t == 255) bsum[blockIdx.x] = s[255];
}

// Scan the chunk totals (nchunks <= 256). Also write rowptr[n] = n_edges.
__global__ __launch_bounds__(256) void scan2(int* __restrict__ bsum, int* __restrict__ rowptr,
                                             int nchunks, int n, int n_edges) {
    __shared__ int s[256];
    const int t = threadIdx.x;
    int v = (t < nchunks) ? bsum[t] : 0;
    s[t] = v; __syncthreads();
    for (int off = 1; off < 256; off <<= 1) {
        int x = (t >= off) ? s[t - off] : 0;
        __syncthreads();
        s[t] += x;
        __syncthreads();
    }
    if (t < nchunks) bsum[t] = s[t] - v;  // exclusive
    if (t == 0) rowptr[n] = n_edges;
}

// Finalize rowptr (+chunk offset), init cursor, compute inv_deg.
__global__ void scan3(int* __restrict__ rowptr, int* __restrict__ cursor, const int* __restrict__ bsum,
                      const int* __restrict__ deg, float* __restrict__ inv_deg, int n) {
    int i = blockIdx.x * blockDim.x + threadIdx.x;
    if (i < n) {
        int r = rowptr[i] + bsum[i / SCAN_CHUNK];
        rowptr[i] = r;
        cursor[i] = r;
        int d = deg[i];
        inv_deg[i] = 1.0f / (float)(d > 0 ? d : 1);
    }
}

__global__ void scatter_kernel(const int* __restrict__ src, const int* __restrict__ dst,
                               int* __restrict__ cursor, int* __restrict__ col, int n_edges) {
    int e = blockIdx.x * blockDim.x + threadIdx.x;
    if (e < n_edges) {
        int d = dst[e];
        int p = atomicAdd(&cursor[d], 1);
        col[p] = src[e];
    }
}

// Gather-aggregate: one W-lane group per node, lane = feature channel.
// EPI: 0 = plain sum; 1 = relu(sum*inv_deg + bias); 2 = sum*inv_deg + bias.
template <int W, int EPI>
__global__ __launch_bounds__(256) void agg_kernel(const float* __restrict__ X, const int* __restrict__ col,
                                                  const int* __restrict__ rowptr,
                                                  const float* __restrict__ inv_deg,
                                                  const float* __restrict__ bias,
                                                  float* __restrict__ out, int n) {
    constexpr int NPB = 256 / W;
    const int node = blockIdx.x * NPB + threadIdx.x / W;
    const int lane = threadIdx.x % W;
    if (node >= n) return;
    const int s = rowptr[node], e = rowptr[node + 1];
    float acc = 0.f;
    int i = s;
    for (; i + 4 <= e; i += 4) {
        int c0 = col[i], c1 = col[i + 1], c2 = col[i + 2], c3 = col[i + 3];
        float a0 = X[(size_t)c0 * W + lane];
        float a1 = X[(size_t)c1 * W + lane];
        float a2 = X[(size_t)c2 * W + lane];
        float a3 = X[(size_t)c3 * W + lane];
        acc += (a0 + a1) + (a2 + a3);
    }
    for (; i < e; ++i) acc += X[(size_t)col[i] * W + lane];
    float v;
    if (EPI == 0) {
        v = acc;
    } else {
        v = acc * inv_deg[node] + bias[lane];
        if (EPI == 1) v = fmaxf(v, 0.f);
    }
    out[(size_t)node * W + lane] = v;
}

// Skinny f32 GEMM: out[nrows x NOUT] = A[nrows x K] @ Wm[K x NOUT] (+ epilogue).
// EPI: 0 = plain; 1 = relu(x*inv_deg[row] + bias[col]).
template <int K, int NOUT, int EPI>
__global__ __launch_bounds__(256) void gemm_kernel(const float* __restrict__ A, const float* __restrict__ Wm,
                                                   const float* __restrict__ bias,
                                                   const float* __restrict__ inv_deg,
                                                   float* __restrict__ out, int nrows) {
    constexpr int BM = 64, BK = 64, NCH = K / BK;
    constexpr int PAD = 68;               // bank-pad: keeps per-k row reads on 2 banks
    __shared__ float As[BM][PAD];
    __shared__ float Ws[BK][NOUT];
    const int t = threadIdx.x;
    constexpr int CG = NOUT / 4;          // col groups (float4 of cols per thread)
    constexpr int RPT = BM / (256 / CG);  // rows per thread
    const int cg = t % CG, rg = t / CG;
    const int row0 = blockIdx.x * BM;

    float acc[RPT][4] = {};

    for (int ch = 0; ch < NCH; ++ch) {
        // Stage A tile (BM x BK) row-major, coalesced float4 loads.
#pragma unroll
        for (int l = 0; l < 4; ++l) {
            int fid = t + l * 256;               // 0..1023 float4 slots
            int r = fid / (BK / 4);
            int c4 = fid % (BK / 4);
            int grow = row0 + r;
            int gr = grow < nrows ? grow : 0;    // safe row for tail block
            float4 v = *(const float4*)&A[(size_t)gr * K + ch * BK + c4 * 4];
            *(float4*)&As[r][c4 * 4] = v;
        }
        // Stage W chunk (BK x NOUT).
#pragma unroll
        for (int l = 0; l < (BK * NOUT / 4) / 256; ++l) {
            int fid = t + l * 256;
            int r = fid / (NOUT / 4);
            int c4 = fid % (NOUT / 4);
            float4 v = *(const float4*)&Wm[(size_t)(ch * BK + r) * NOUT + c4 * 4];
            *(float4*)&Ws[r][c4 * 4] = v;
        }
        __syncthreads();
#pragma unroll 8
        for (int k = 0; k < BK; ++k) {
            float4 w = *(float4*)&Ws[k][cg * 4];
#pragma unroll
            for (int i = 0; i < RPT; ++i) {
                float a = As[rg * RPT + i][k];
                acc[i][0] += a * w.x;
                acc[i][1] += a * w.y;
                acc[i][2] += a * w.z;
                acc[i][3] += a * w.w;
            }
        }
        __syncthreads();
    }

#pragma unroll
    for (int i = 0; i < RPT; ++i) {
        int r = row0 + rg * RPT + i;
        if (r < nrows) {
            float x0 = acc[i][0], x1 = acc[i][1], x2 = acc[i][2], x3 = acc[i][3];
            if (EPI == 1) {
                float sc = inv_deg[r];
                x0 = fmaxf(x0 * sc + bias[cg * 4 + 0], 0.f);
                x1 = fmaxf(x1 * sc + bias[cg * 4 + 1], 0.f);
                x2 = fmaxf(x2 * sc + bias[cg * 4 + 2], 0.f);
                x3 = fmaxf(x3 * sc + bias[cg * 4 + 3], 0.f);
            }
            float4 v = make_float4(x0, x1, x2, x3);
            *(float4*)&out[(size_t)r * NOUT + cg * 4] = v;
        }
    }
}

extern "C" void kernel_launch(void* const* d_in, const int* in_sizes, int n_in,
                              void* d_out, int out_size, void* d_ws, size_t ws_size,
                              hipStream_t stream) {
    const float* feat = (const float*)d_in[0];
    const float* W0   = (const float*)d_in[1];
    const float* b0   = (const float*)d_in[2];
    const float* W1   = (const float*)d_in[3];
    const float* b1   = (const float*)d_in[4];
    const float* W2   = (const float*)d_in[5];
    const float* b2   = (const float*)d_in[6];
    const int*   src  = (const int*)d_in[7];
    const int*   dstv = (const int*)d_in[8];

    const int n = in_sizes[0] / 256;   // 100000
    const int e = in_sizes[7];         // 1600000

    // Workspace carve-up (256B aligned).
    char* base = (char*)d_ws;
    size_t off = 0;
    auto alloc = [&](size_t bytes) -> char* {
        char* p = base + off;
        off += (bytes + 255) & ~(size_t)255;
        return p;
    };
    int*   deg    = (int*)alloc((size_t)n * 4);
    float* invd   = (float*)alloc((size_t)n * 4);
    int*   rowptr = (int*)alloc((size_t)(n + 1) * 4);
    int*   cursor = (int*)alloc((size_t)n * 4);
    int*   bsum   = (int*)alloc(1024);
    int*   col    = (int*)alloc((size_t)e * 4);
    float* bufA   = (float*)alloc((size_t)n * 64 * 4);
    float* bufB   = (float*)alloc((size_t)n * 64 * 4);
    (void)ws_size;

    const int nchunks = (n + SCAN_CHUNK - 1) / SCAN_CHUNK;  // 98 (<=256 assumed)

    // --- CSR build ---
    zero_i32<<<(n + 255) / 256, 256, 0, stream>>>(deg, n);
    hist_kernel<<<(e + 255) / 256, 256, 0, stream>>>(dstv, deg, e);
    scan1<<<nchunks, 256, 0, stream>>>(deg, rowptr, bsum, n);
    scan2<<<1, 256, 0, stream>>>(bsum, rowptr, nchunks, n, e);
    scan3<<<(n + 255) / 256, 256, 0, stream>>>(rowptr, cursor, bsum, deg, invd, n);
    scatter_kernel<<<(e + 255) / 256, 256, 0, stream>>>(src, dstv, cursor, col, e);

    const int gemm_blocks = (n + 63) / 64;

    // --- Layer 0: H = feat@W0 ; X1 = relu(agg(H)*inv + b0) ---
    gemm_kernel<256, 64, 0><<<gemm_blocks, 256, 0, stream>>>(feat, W0, nullptr, nullptr, bufA, n);
    agg_kernel<64, 1><<<(n + 3) / 4, 256, 0, stream>>>(bufA, col, rowptr, invd, b0, bufB, n);

    // --- Layer 1: A2 = agg(X1) ; X2 = relu((A2@W1)*inv + b1) ---
    agg_kernel<64, 0><<<(n + 3) / 4, 256, 0, stream>>>(bufB, col, rowptr, nullptr, nullptr, bufA, n);
    gemm_kernel<64, 64, 1><<<gemm_blocks, 256, 0, stream>>>(bufA, W1, b1, invd, bufB, n);

    // --- Layer 2: H2 = X2@W2 ; out = agg(H2)*inv + b2 ---
    gemm_kernel<64, 32, 0><<<gemm_blocks, 256, 0, stream>>>(bufB, W2, nullptr, nullptr, bufA, n);
    agg_kernel<32, 2><<<(n + 7) / 8, 256, 0, stream>>>(bufA, col, rowptr, invd, b2, (float*)d_out, n);
}

// Round 2
// 321.582 us; speedup vs baseline: 1.4677x; 1.4677x over previous
//
#include <hip/hip_runtime.h>
#include <hip/hip_bf16.h>

// GCN: 3 layers over fixed graph (N=100000 nodes, E=1600000 edges).
// CSR build via bucketed sort (128 nodes/bucket): no global atomics,
// all histogram/cursor traffic in LDS. Then gather-only aggregations.

constexpr int NB_SHIFT = 7;          // 128 nodes per bucket
constexpr int EPB = 8192;            // edges per block in pass A/B
constexpr int MAXNB = 800;           // >= ceil(100000/128)=782

// Pass A: per-block LDS histogram over buckets -> C_T[bucket][block] counts.
__global__ __launch_bounds__(256) void passA_hist(const int* __restrict__ dst, int* __restrict__ C_T,
                                                  int nb, int nblk, int n_edges) {
    __shared__ int h[MAXNB];
    for (int i = threadIdx.x; i < nb; i += 256) h[i] = 0;
    __syncthreads();
    const int e0 = blockIdx.x * EPB;
    const int e1 = min(e0 + EPB, n_edges);
    for (int i = e0 + threadIdx.x; i < e1; i += 256)
        atomicAdd(&h[dst[i] >> NB_SHIFT], 1);
    __syncthreads();
    for (int i = threadIdx.x; i < nb; i += 256)
        C_T[i * nblk + blockIdx.x] = h[i];
}

// Per-bucket exclusive scan across blocks (in place); row totals out.
__global__ __launch_bounds__(256) void bucket_prefix(int* __restrict__ C_T, int* __restrict__ totals,
                                                     int nblk) {
    __shared__ int s[256];
    const int b = blockIdx.x, t = threadIdx.x;
    int v = (t < nblk) ? C_T[b * nblk + t] : 0;
    s[t] = v; __syncthreads();
    for (int off = 1; off < 256; off <<= 1) {
        int x = (t >= off) ? s[t - off] : 0;
        __syncthreads();
        s[t] += x;
        __syncthreads();
    }
    if (t < nblk) C_T[b * nblk + t] = s[t] - v;
    if (t == 255) totals[b] = s[255];
}

// Exclusive scan of bucket totals -> base[nb+1]; also rowptr[n]=E.
__global__ __launch_bounds__(256) void scan_base(const int* __restrict__ totals, int* __restrict__ base_out,
                                                 int* __restrict__ rowptr, int nb, int n, int n_edges) {
    __shared__ int s[256];
    const int t = threadIdx.x;
    int v[4]; int ts = 0;
#pragma unroll
    for (int j = 0; j < 4; ++j) { int i = t * 4 + j; v[j] = (i < nb) ? totals[i] : 0; ts += v[j]; }
    s[t] = ts; __syncthreads();
    for (int off = 1; off < 256; off <<= 1) {
        int x = (t >= off) ? s[t - off] : 0;
        __syncthreads();
        s[t] += x;
        __syncthreads();
    }
    int run = s[t] - ts;
#pragma unroll
    for (int j = 0; j < 4; ++j) { int i = t * 4 + j; if (i < nb) base_out[i] = run; run += v[j]; }
    if (t == 255) base_out[nb] = s[255];
    if (t == 0) rowptr[n] = n_edges;
}

// Pass B: scatter (src,dst) into bucket-sorted order using LDS cursors.
__global__ __launch_bounds__(256) void passB_scatter(const int* __restrict__ src, const int* __restrict__ dst,
                                                     const int* __restrict__ C_T, const int* __restrict__ base,
                                                     int2* __restrict__ sorted, int nb, int nblk, int n_edges) {
    __shared__ int cur[MAXNB];
    const int blk = blockIdx.x;
    for (int i = threadIdx.x; i < nb; i += 256) cur[i] = base[i] + C_T[i * nblk + blk];
    __syncthreads();
    const int e0 = blk * EPB;
    const int e1 = min(e0 + EPB, n_edges);
    for (int i = e0 + threadIdx.x; i < e1; i += 256) {
        int d = dst[i];
        int p = atomicAdd(&cur[d >> NB_SHIFT], 1);
        sorted[p] = make_int2(src[i], d);
    }
}

// Pass C: per-bucket counting sort in LDS -> rowptr, col, inv_deg.
__global__ __launch_bounds__(256) void passC_build(const int2* __restrict__ sorted, const int* __restrict__ base,
                                                   int* __restrict__ rowptr, int* __restrict__ col,
                                                   float* __restrict__ invd, int n) {
    __shared__ int degl[128];
    __shared__ int s[256];
    __shared__ int curl[128];
    const int b = blockIdx.x, t = threadIdx.x;
    const int node0 = b << NB_SHIFT;
    const int nn = min(128, n - node0);
    const int e0 = base[b], e1 = base[b + 1];
    if (t < 128) degl[t] = 0;
    __syncthreads();
    for (int i = e0 + t; i < e1; i += 256)
        atomicAdd(&degl[sorted[i].y - node0], 1);
    __syncthreads();
    int d = (t < 128) ? degl[t] : 0;
    s[t] = d; __syncthreads();
    for (int off = 1; off < 128; off <<= 1) {
        int x = (t >= off) ? s[t - off] : 0;
        __syncthreads();
        s[t] += x;
        __syncthreads();
    }
    if (t < 128) {
        int excl = s[t] - d;
        curl[t] = excl;
        if (t < nn) {
            rowptr[node0 + t] = e0 + excl;
            invd[node0 + t] = 1.0f / (float)(d > 0 ? d : 1);
        }
    }
    __syncthreads();
    for (int i = e0 + t; i < e1; i += 256) {
        int2 ed = sorted[i];
        int p = atomicAdd(&curl[ed.y - node0], 1);
        col[e0 + p] = ed.x;
    }
}

// Gather-aggregate: one W-lane group per node, lane = feature channel.
// EPI: 0 = plain sum; 1 = relu(sum*inv_deg + bias); 2 = sum*inv_deg + bias.
template <int W, int EPI>
__global__ __launch_bounds__(256) void agg_kernel(const float* __restrict__ X, const int* __restrict__ col,
                                                  const int* __restrict__ rowptr,
                                                  const float* __restrict__ inv_deg,
                                                  const float* __restrict__ bias,
                                                  float* __restrict__ out, int n) {
    constexpr int NPB = 256 / W;
    const int node = blockIdx.x * NPB + threadIdx.x / W;
    const int lane = threadIdx.x % W;
    if (node >= n) return;
    const int s = rowptr[node], e = rowptr[node + 1];
    float acc = 0.f;
    int i = s;
    for (; i + 4 <= e; i += 4) {
        int c0 = col[i], c1 = col[i + 1], c2 = col[i + 2], c3 = col[i + 3];
        float a0 = X[(size_t)c0 * W + lane];
        float a1 = X[(size_t)c1 * W + lane];
        float a2 = X[(size_t)c2 * W + lane];
        float a3 = X[(size_t)c3 * W + lane];
        acc += (a0 + a1) + (a2 + a3);
    }
    for (; i < e; ++i) acc += X[(size_t)col[i] * W + lane];
    float v;
    if (EPI == 0) {
        v = acc;
    } else {
        v = acc * inv_deg[node] + bias[lane];
        if (EPI == 1) v = fmaxf(v, 0.f);
    }
    out[(size_t)node * W + lane] = v;
}

// Skinny f32 GEMM: out[nrows x NOUT] = A[nrows x K] @ Wm[K x NOUT] (+ epilogue).
// EPI: 0 = plain; 1 = relu(x*inv_deg[row] + bias[col]).
template <int K, int NOUT, int EPI>
__global__ __launch_bounds__(256) void gemm_kernel(const float* __restrict__ A, const float* __restrict__ Wm,
                                                   const float* __restrict__ bias,
                                                   const float* __restrict__ inv_deg,
                                                   float* __restrict__ out, int nrows) {
    constexpr int BM = 64, BK = 64, NCH = K / BK;
    constexpr int PAD = 68;               // bank-pad: keeps per-k row reads on 2 banks
    __shared__ float As[BM][PAD];
    __shared__ float Ws[BK][NOUT];
    const int t = threadIdx.x;
    constexpr int CG = NOUT / 4;          // col groups (float4 of cols per thread)
    constexpr int RPT = BM / (256 / CG);  // rows per thread
    const int cg = t % CG, rg = t / CG;
    const int row0 = blockIdx.x * BM;

    float acc[RPT][4] = {};

    for (int ch = 0; ch < NCH; ++ch) {
#pragma unroll
        for (int l = 0; l < 4; ++l) {
            int fid = t + l * 256;               // 0..1023 float4 slots
            int r = fid / (BK / 4);
            int c4 = fid % (BK / 4);
            int grow = row0 + r;
            int gr = grow < nrows ? grow : 0;    // safe row for tail block
            float4 v = *(const float4*)&A[(size_t)gr * K + ch * BK + c4 * 4];
            *(float4*)&As[r][c4 * 4] = v;
        }
#pragma unroll
        for (int l = 0; l < (BK * NOUT / 4) / 256; ++l) {
            int fid = t + l * 256;
            int r = fid / (NOUT / 4);
            int c4 = fid % (NOUT / 4);
            float4 v = *(const float4*)&Wm[(size_t)(ch * BK + r) * NOUT + c4 * 4];
            *(float4*)&Ws[r][c4 * 4] = v;
        }
        __syncthreads();
#pragma unroll 8
        for (int k = 0; k < BK; ++k) {
            float4 w = *(float4*)&Ws[k][cg * 4];
#pragma unroll
            for (int i = 0; i < RPT; ++i) {
                float a = As[rg * RPT + i][k];
                acc[i][0] += a * w.x;
                acc[i][1] += a * w.y;
                acc[i][2] += a * w.z;
                acc[i][3] += a * w.w;
            }
        }
        __syncthreads();
    }

#pragma unroll
    for (int i = 0; i < RPT; ++i) {
        int r = row0 + rg * RPT + i;
        if (r < nrows) {
            float x0 = acc[i][0], x1 = acc[i][1], x2 = acc[i][2], x3 = acc[i][3];
            if (EPI == 1) {
                float sc = inv_deg[r];
                x0 = fmaxf(x0 * sc + bias[cg * 4 + 0], 0.f);
                x1 = fmaxf(x1 * sc + bias[cg * 4 + 1], 0.f);
                x2 = fmaxf(x2 * sc + bias[cg * 4 + 2], 0.f);
                x3 = fmaxf(x3 * sc + bias[cg * 4 + 3], 0.f);
            }
            float4 v = make_float4(x0, x1, x2, x3);
            *(float4*)&out[(size_t)r * NOUT + cg * 4] = v;
        }
    }
}

extern "C" void kernel_launch(void* const* d_in, const int* in_sizes, int n_in,
                              void* d_out, int out_size, void* d_ws, size_t ws_size,
                              hipStream_t stream) {
    const float* feat = (const float*)d_in[0];
    const float* W0   = (const float*)d_in[1];
    const float* b0   = (const float*)d_in[2];
    const float* W1   = (const float*)d_in[3];
    const float* b1   = (const float*)d_in[4];
    const float* W2   = (const float*)d_in[5];
    const float* b2   = (const float*)d_in[6];
    const int*   src  = (const int*)d_in[7];
    const int*   dstv = (const int*)d_in[8];

    const int n = in_sizes[0] / 256;   // 100000
    const int e = in_sizes[7];         // 1600000

    const int nb   = (n + 127) >> NB_SHIFT;        // 782 buckets
    const int nblk = (e + EPB - 1) / EPB;          // 196 blocks

    // Workspace carve-up (256B aligned).
    char* base_p = (char*)d_ws;
    size_t off = 0;
    auto alloc = [&](size_t bytes) -> char* {
        char* p = base_p + off;
        off += (bytes + 255) & ~(size_t)255;
        return p;
    };
    float* invd   = (float*)alloc((size_t)n * 4);
    int*   rowptr = (int*)alloc((size_t)(n + 1) * 4);
    int*   bbase  = (int*)alloc((size_t)(MAXNB + 1) * 4);
    int*   totals = (int*)alloc((size_t)MAXNB * 4);
    int*   col    = (int*)alloc((size_t)e * 4);      // C_T aliases the front of col
    float* bufA   = (float*)alloc((size_t)n * 64 * 4);  // sorted aliases the front of bufA
    float* bufB   = (float*)alloc((size_t)n * 64 * 4);
    (void)ws_size;

    int*  C_T    = col;            // nb*nblk ints (613KB) — dead before col is written
    int2* sorted = (int2*)bufA;    // e*8 bytes (12.8MB) — dead before gemm0 writes bufA

    // --- CSR build (bucketed sort, no global atomics) ---
    passA_hist   <<<nblk, 256, 0, stream>>>(dstv, C_T, nb, nblk, e);
    bucket_prefix<<<nb,   256, 0, stream>>>(C_T, totals, nblk);
    scan_base    <<<1,    256, 0, stream>>>(totals, bbase, rowptr, nb, n, e);
    passB_scatter<<<nblk, 256, 0, stream>>>(src, dstv, C_T, bbase, sorted, nb, nblk, e);
    passC_build  <<<nb,   256, 0, stream>>>(sorted, bbase, rowptr, col, invd, n);

    const int gemm_blocks = (n + 63) / 64;

    // --- Layer 0: H = feat@W0 ; X1 = relu(agg(H)*inv + b0) ---
    gemm_kernel<256, 64, 0><<<gemm_blocks, 256, 0, stream>>>(feat, W0, nullptr, nullptr, bufA, n);
    agg_kernel<64, 1><<<(n + 3) / 4, 256, 0, stream>>>(bufA, col, rowptr, invd, b0, bufB, n);

    // --- Layer 1: A2 = agg(X1) ; X2 = relu((A2@W1)*inv + b1) ---
    agg_kernel<64, 0><<<(n + 3) / 4, 256, 0, stream>>>(bufB, col, rowptr, nullptr, nullptr, bufA, n);
    gemm_kernel<64, 64, 1><<<gemm_blocks, 256, 0, stream>>>(bufA, W1, b1, invd, bufB, n);

    // --- Layer 2: H2 = X2@W2 ; out = agg(H2)*inv + b2 ---
    gemm_kernel<64, 32, 0><<<gemm_blocks, 256, 0, stream>>>(bufB, W2, nullptr, nullptr, bufA, n);
    agg_kernel<32, 2><<<(n + 7) / 8, 256, 0, stream>>>(bufA, col, rowptr, invd, b2, (float*)d_out, n);
}

// Round 3
// 301.801 us; speedup vs baseline: 1.5639x; 1.0655x over previous
//
#include <hip/hip_runtime.h>
#include <hip/hip_bf16.h>
#include <hip/hip_fp16.h>

// GCN: 3 layers over fixed graph (N=100000 nodes, E=1600000 edges).
// CSR build via bucketed sort (no global atomics), gather-only aggregation.
// All aggregation operands stored fp16 (halves cache-fabric gather bytes);
// accumulation and GEMM math stay f32.

constexpr int NB_SHIFT = 7;          // 128 nodes per bucket
constexpr int EPB = 8192;            // edges per block in pass A/B
constexpr int MAXNB = 800;           // >= ceil(100000/128)=782

// Pass A: per-block LDS histogram over buckets -> C_T[bucket][block] counts.
__global__ __launch_bounds__(256) void passA_hist(const int* __restrict__ dst, int* __restrict__ C_T,
                                                  int nb, int nblk, int n_edges) {
    __shared__ int h[MAXNB];
    for (int i = threadIdx.x; i < nb; i += 256) h[i] = 0;
    __syncthreads();
    const int e0 = blockIdx.x * EPB;
    const int e1 = min(e0 + EPB, n_edges);
    for (int i = e0 + threadIdx.x; i < e1; i += 256)
        atomicAdd(&h[dst[i] >> NB_SHIFT], 1);
    __syncthreads();
    for (int i = threadIdx.x; i < nb; i += 256)
        C_T[i * nblk + blockIdx.x] = h[i];
}

// Per-bucket exclusive scan across blocks (in place); row totals out.
__global__ __launch_bounds__(256) void bucket_prefix(int* __restrict__ C_T, int* __restrict__ totals,
                                                     int nblk) {
    __shared__ int s[256];
    const int b = blockIdx.x, t = threadIdx.x;
    int v = (t < nblk) ? C_T[b * nblk + t] : 0;
    s[t] = v; __syncthreads();
    for (int off = 1; off < 256; off <<= 1) {
        int x = (t >= off) ? s[t - off] : 0;
        __syncthreads();
        s[t] += x;
        __syncthreads();
    }
    if (t < nblk) C_T[b * nblk + t] = s[t] - v;
    if (t == 255) totals[b] = s[255];
}

// Exclusive scan of bucket totals -> base[nb+1]; also rowptr[n]=E.
__global__ __launch_bounds__(256) void scan_base(const int* __restrict__ totals, int* __restrict__ base_out,
                                                 int* __restrict__ rowptr, int nb, int n, int n_edges) {
    __shared__ int s[256];
    const int t = threadIdx.x;
    int v[4]; int ts = 0;
#pragma unroll
    for (int j = 0; j < 4; ++j) { int i = t * 4 + j; v[j] = (i < nb) ? totals[i] : 0; ts += v[j]; }
    s[t] = ts; __syncthreads();
    for (int off = 1; off < 256; off <<= 1) {
        int x = (t >= off) ? s[t - off] : 0;
        __syncthreads();
        s[t] += x;
        __syncthreads();
    }
    int run = s[t] - ts;
#pragma unroll
    for (int j = 0; j < 4; ++j) { int i = t * 4 + j; if (i < nb) base_out[i] = run; run += v[j]; }
    if (t == 255) base_out[nb] = s[255];
    if (t == 0) rowptr[n] = n_edges;
}

// Pass B: scatter (src,dst) into bucket-sorted order using LDS cursors.
__global__ __launch_bounds__(256) void passB_scatter(const int* __restrict__ src, const int* __restrict__ dst,
                                                     const int* __restrict__ C_T, const int* __restrict__ base,
                                                     int2* __restrict__ sorted, int nb, int nblk, int n_edges) {
    __shared__ int cur[MAXNB];
    const int blk = blockIdx.x;
    for (int i = threadIdx.x; i < nb; i += 256) cur[i] = base[i] + C_T[i * nblk + blk];
    __syncthreads();
    const int e0 = blk * EPB;
    const int e1 = min(e0 + EPB, n_edges);
    for (int i = e0 + threadIdx.x; i < e1; i += 256) {
        int d = dst[i];
        int p = atomicAdd(&cur[d >> NB_SHIFT], 1);
        sorted[p] = make_int2(src[i], d);
    }
}

// Pass C: per-bucket counting sort in LDS -> rowptr, col, inv_deg.
__global__ __launch_bounds__(256) void passC_build(const int2* __restrict__ sorted, const int* __restrict__ base,
                                                   int* __restrict__ rowptr, int* __restrict__ col,
                                                   float* __restrict__ invd, int n) {
    __shared__ int degl[128];
    __shared__ int s[256];
    __shared__ int curl[128];
    const int b = blockIdx.x, t = threadIdx.x;
    const int node0 = b << NB_SHIFT;
    const int nn = min(128, n - node0);
    const int e0 = base[b], e1 = base[b + 1];
    if (t < 128) degl[t] = 0;
    __syncthreads();
    for (int i = e0 + t; i < e1; i += 256)
        atomicAdd(&degl[sorted[i].y - node0], 1);
    __syncthreads();
    int d = (t < 128) ? degl[t] : 0;
    s[t] = d; __syncthreads();
    for (int off = 1; off < 128; off <<= 1) {
        int x = (t >= off) ? s[t - off] : 0;
        __syncthreads();
        s[t] += x;
        __syncthreads();
    }
    if (t < 128) {
        int excl = s[t] - d;
        curl[t] = excl;
        if (t < nn) {
            rowptr[node0 + t] = e0 + excl;
            invd[node0 + t] = 1.0f / (float)(d > 0 ? d : 1);
        }
    }
    __syncthreads();
    for (int i = e0 + t; i < e1; i += 256) {
        int2 ed = sorted[i];
        int p = atomicAdd(&curl[ed.y - node0], 1);
        col[e0 + p] = ed.x;
    }
}

// ---- type helpers ----
__device__ inline float4 load4(const float* p) { return *(const float4*)p; }
__device__ inline float4 load4(const __half* p) {
    __half2 a = *(const __half2*)p;
    __half2 b = *(const __half2*)(p + 2);
    float2 fa = __half22float2(a), fb = __half22float2(b);
    return make_float4(fa.x, fa.y, fb.x, fb.y);
}
__device__ inline void store4(float* p, float x0, float x1, float x2, float x3) {
    *(float4*)p = make_float4(x0, x1, x2, x3);
}
__device__ inline void store4(__half* p, float x0, float x1, float x2, float x3) {
    union { __half h[4]; int2 i2; } u;
    u.h[0] = __float2half(x0); u.h[1] = __float2half(x1);
    u.h[2] = __float2half(x2); u.h[3] = __float2half(x3);
    *(int2*)p = u.i2;
}
__device__ inline void store1(float* p, float v) { *p = v; }
__device__ inline void store1(__half* p, float v) { *p = __float2half(v); }

// Gather-aggregate: one W-lane group per node, lane = feature channel.
// X is fp16. EPI: 0 = plain sum; 1 = relu(sum*inv_deg + bias); 2 = sum*inv_deg + bias.
template <int W, int EPI, typename OutT>
__global__ __launch_bounds__(256) void agg_kernel(const __half* __restrict__ X, const int* __restrict__ col,
                                                  const int* __restrict__ rowptr,
                                                  const float* __restrict__ inv_deg,
                                                  const float* __restrict__ bias,
                                                  OutT* __restrict__ out, int n) {
    constexpr int NPB = 256 / W;
    const int node = blockIdx.x * NPB + threadIdx.x / W;
    const int lane = threadIdx.x % W;
    if (node >= n) return;
    const int s = rowptr[node], e = rowptr[node + 1];
    float acc = 0.f;
    int i = s;
    for (; i + 4 <= e; i += 4) {
        int c0 = col[i], c1 = col[i + 1], c2 = col[i + 2], c3 = col[i + 3];
        float a0 = __half2float(X[(size_t)c0 * W + lane]);
        float a1 = __half2float(X[(size_t)c1 * W + lane]);
        float a2 = __half2float(X[(size_t)c2 * W + lane]);
        float a3 = __half2float(X[(size_t)c3 * W + lane]);
        acc += (a0 + a1) + (a2 + a3);
    }
    for (; i < e; ++i) acc += __half2float(X[(size_t)col[i] * W + lane]);
    float v;
    if (EPI == 0) {
        v = acc;
    } else {
        v = acc * inv_deg[node] + bias[lane];
        if (EPI == 1) v = fmaxf(v, 0.f);
    }
    store1(&out[(size_t)node * W + lane], v);
}

// Skinny f32 GEMM: out[nrows x NOUT] = A[nrows x K] @ Wm[K x NOUT] (+ epilogue).
// A may be f32 or fp16 (converted at LDS stage); math f32.
// EPI: 0 = plain; 1 = relu(x*inv_deg[row] + bias[col]).
template <int K, int NOUT, int EPI, typename InT, typename OutT>
__global__ __launch_bounds__(256) void gemm_kernel(const InT* __restrict__ A, const float* __restrict__ Wm,
                                                   const float* __restrict__ bias,
                                                   const float* __restrict__ inv_deg,
                                                   OutT* __restrict__ out, int nrows) {
    constexpr int BM = 64, BK = 64, NCH = K / BK;
    constexpr int PAD = 68;               // bank-pad: keeps per-k row reads on 2 banks
    __shared__ float As[BM][PAD];
    __shared__ float Ws[BK][NOUT];
    const int t = threadIdx.x;
    constexpr int CG = NOUT / 4;          // col groups (float4 of cols per thread)
    constexpr int RPT = BM / (256 / CG);  // rows per thread
    const int cg = t % CG, rg = t / CG;
    const int row0 = blockIdx.x * BM;

    float acc[RPT][4] = {};

    for (int ch = 0; ch < NCH; ++ch) {
#pragma unroll
        for (int l = 0; l < 4; ++l) {
            int fid = t + l * 256;               // 0..1023 4-elem slots
            int r = fid / (BK / 4);
            int c4 = fid % (BK / 4);
            int grow = row0 + r;
            int gr = grow < nrows ? grow : 0;    // safe row for tail block
            float4 v = load4(&A[(size_t)gr * K + ch * BK + c4 * 4]);
            *(float4*)&As[r][c4 * 4] = v;
        }
#pragma unroll
        for (int l = 0; l < (BK * NOUT / 4) / 256; ++l) {
            int fid = t + l * 256;
            int r = fid / (NOUT / 4);
            int c4 = fid % (NOUT / 4);
            float4 v = *(const float4*)&Wm[(size_t)(ch * BK + r) * NOUT + c4 * 4];
            *(float4*)&Ws[r][c4 * 4] = v;
        }
        __syncthreads();
#pragma unroll 8
        for (int k = 0; k < BK; ++k) {
            float4 w = *(float4*)&Ws[k][cg * 4];
#pragma unroll
            for (int i = 0; i < RPT; ++i) {
                float a = As[rg * RPT + i][k];
                acc[i][0] += a * w.x;
                acc[i][1] += a * w.y;
                acc[i][2] += a * w.z;
                acc[i][3] += a * w.w;
            }
        }
        __syncthreads();
    }

#pragma unroll
    for (int i = 0; i < RPT; ++i) {
        int r = row0 + rg * RPT + i;
        if (r < nrows) {
            float x0 = acc[i][0], x1 = acc[i][1], x2 = acc[i][2], x3 = acc[i][3];
            if (EPI == 1) {
                float sc = inv_deg[r];
                x0 = fmaxf(x0 * sc + bias[cg * 4 + 0], 0.f);
                x1 = fmaxf(x1 * sc + bias[cg * 4 + 1], 0.f);
                x2 = fmaxf(x2 * sc + bias[cg * 4 + 2], 0.f);
                x3 = fmaxf(x3 * sc + bias[cg * 4 + 3], 0.f);
            }
            store4(&out[(size_t)r * NOUT + cg * 4], x0, x1, x2, x3);
        }
    }
}

extern "C" void kernel_launch(void* const* d_in, const int* in_sizes, int n_in,
                              void* d_out, int out_size, void* d_ws, size_t ws_size,
                              hipStream_t stream) {
    const float* feat = (const float*)d_in[0];
    const float* W0   = (const float*)d_in[1];
    const float* b0   = (const float*)d_in[2];
    const float* W1   = (const float*)d_in[3];
    const float* b1   = (const float*)d_in[4];
    const float* W2   = (const float*)d_in[5];
    const float* b2   = (const float*)d_in[6];
    const int*   src  = (const int*)d_in[7];
    const int*   dstv = (const int*)d_in[8];

    const int n = in_sizes[0] / 256;   // 100000
    const int e = in_sizes[7];         // 1600000

    const int nb   = (n + 127) >> NB_SHIFT;        // 782 buckets
    const int nblk = (e + EPB - 1) / EPB;          // 196 blocks

    // Workspace carve-up (256B aligned).
    char* base_p = (char*)d_ws;
    size_t off = 0;
    auto alloc = [&](size_t bytes) -> char* {
        char* p = base_p + off;
        off += (bytes + 255) & ~(size_t)255;
        return p;
    };
    float*  invd   = (float*)alloc((size_t)n * 4);
    int*    rowptr = (int*)alloc((size_t)(n + 1) * 4);
    int*    bbase  = (int*)alloc((size_t)(MAXNB + 1) * 4);
    int*    totals = (int*)alloc((size_t)MAXNB * 4);
    int*    col    = (int*)alloc((size_t)e * 4);          // C_T aliases col
    __half* bufH1  = (__half*)alloc((size_t)n * 64 * 2);  // H, later X2
    __half* bufH2  = (__half*)alloc((size_t)n * 64 * 2);  // X1, later H2
    float*  bufF1  = (float*)alloc((size_t)n * 64 * 4);   // sorted aliases; later A2
    (void)ws_size;

    int*  C_T    = col;            // nb*nblk ints (613KB) — dead before col is written
    int2* sorted = (int2*)bufF1;   // e*8 B (12.8MB) — dead before A2 is written

    // --- CSR build (bucketed sort, no global atomics) ---
    passA_hist   <<<nblk, 256, 0, stream>>>(dstv, C_T, nb, nblk, e);
    bucket_prefix<<<nb,   256, 0, stream>>>(C_T, totals, nblk);
    scan_base    <<<1,    256, 0, stream>>>(totals, bbase, rowptr, nb, n, e);
    passB_scatter<<<nblk, 256, 0, stream>>>(src, dstv, C_T, bbase, sorted, nb, nblk, e);
    passC_build  <<<nb,   256, 0, stream>>>(sorted, bbase, rowptr, col, invd, n);

    const int gemm_blocks = (n + 63) / 64;

    // --- Layer 0: H = feat@W0 (f32->h) ; X1 = relu(agg(H)*inv + b0) (h) ---
    gemm_kernel<256, 64, 0, float, __half><<<gemm_blocks, 256, 0, stream>>>(feat, W0, nullptr, nullptr, bufH1, n);
    agg_kernel<64, 1, __half><<<(n + 3) / 4, 256, 0, stream>>>(bufH1, col, rowptr, invd, b0, bufH2, n);

    // --- Layer 1: A2 = agg(X1) (f32) ; X2 = relu((A2@W1)*inv + b1) (h) ---
    agg_kernel<64, 0, float><<<(n + 3) / 4, 256, 0, stream>>>(bufH2, col, rowptr, nullptr, nullptr, bufF1, n);
    gemm_kernel<64, 64, 1, float, __half><<<gemm_blocks, 256, 0, stream>>>(bufF1, W1, b1, invd, bufH1, n);

    // --- Layer 2: H2 = X2@W2 (h->h) ; out = agg(H2)*inv + b2 (f32) ---
    gemm_kernel<64, 32, 0, __half, __half><<<gemm_blocks, 256, 0, stream>>>(bufH1, W2, nullptr, nullptr, bufH2, n);
    agg_kernel<32, 2, float><<<(n + 7) / 8, 256, 0, stream>>>(bufH2, col, rowptr, invd, b2, (float*)d_out, n);
}

// Round 4
// 296.910 us; speedup vs baseline: 1.5897x; 1.0165x over previous
//
#include <hip/hip_runtime.h>
#include <hip/hip_bf16.h>
#include <hip/hip_fp16.h>

// GCN: 3 layers over fixed graph (N=100000 nodes, E=1600000 edges).
// CSR build via bucketed sort (no global atomics), gather-only aggregation.
// Aggregation operands stored fp16; each lane gathers 8B (4 halves) so a
// wave keeps 4-8 cache lines in flight per issue (MLP, latency-bound fix).

constexpr int NB_SHIFT = 7;          // 128 nodes per bucket
constexpr int EPB = 8192;            // edges per block in pass A/B
constexpr int MAXNB = 800;           // >= ceil(100000/128)=782

// Pass A: per-block LDS histogram over buckets -> C_T[bucket][block] counts.
__global__ __launch_bounds__(256) void passA_hist(const int* __restrict__ dst, int* __restrict__ C_T,
                                                  int nb, int nblk, int n_edges) {
    __shared__ int h[MAXNB];
    for (int i = threadIdx.x; i < nb; i += 256) h[i] = 0;
    __syncthreads();
    const int e0 = blockIdx.x * EPB;
    const int e1 = min(e0 + EPB, n_edges);
    for (int i = e0 + threadIdx.x; i < e1; i += 256)
        atomicAdd(&h[dst[i] >> NB_SHIFT], 1);
    __syncthreads();
    for (int i = threadIdx.x; i < nb; i += 256)
        C_T[i * nblk + blockIdx.x] = h[i];
}

// Per-bucket exclusive scan across blocks (in place); row totals out.
__global__ __launch_bounds__(256) void bucket_prefix(int* __restrict__ C_T, int* __restrict__ totals,
                                                     int nblk) {
    __shared__ int s[256];
    const int b = blockIdx.x, t = threadIdx.x;
    int v = (t < nblk) ? C_T[b * nblk + t] : 0;
    s[t] = v; __syncthreads();
    for (int off = 1; off < 256; off <<= 1) {
        int x = (t >= off) ? s[t - off] : 0;
        __syncthreads();
        s[t] += x;
        __syncthreads();
    }
    if (t < nblk) C_T[b * nblk + t] = s[t] - v;
    if (t == 255) totals[b] = s[255];
}

// Exclusive scan of bucket totals -> base[nb+1]; also rowptr[n]=E.
__global__ __launch_bounds__(256) void scan_base(const int* __restrict__ totals, int* __restrict__ base_out,
                                                 int* __restrict__ rowptr, int nb, int n, int n_edges) {
    __shared__ int s[256];
    const int t = threadIdx.x;
    int v[4]; int ts = 0;
#pragma unroll
    for (int j = 0; j < 4; ++j) { int i = t * 4 + j; v[j] = (i < nb) ? totals[i] : 0; ts += v[j]; }
    s[t] = ts; __syncthreads();
    for (int off = 1; off < 256; off <<= 1) {
        int x = (t >= off) ? s[t - off] : 0;
        __syncthreads();
        s[t] += x;
        __syncthreads();
    }
    int run = s[t] - ts;
#pragma unroll
    for (int j = 0; j < 4; ++j) { int i = t * 4 + j; if (i < nb) base_out[i] = run; run += v[j]; }
    if (t == 255) base_out[nb] = s[255];
    if (t == 0) rowptr[n] = n_edges;
}

// Pass B: scatter (src,dst) into bucket-sorted order using LDS cursors.
__global__ __launch_bounds__(256) void passB_scatter(const int* __restrict__ src, const int* __restrict__ dst,
                                                     const int* __restrict__ C_T, const int* __restrict__ base,
                                                     int2* __restrict__ sorted, int nb, int nblk, int n_edges) {
    __shared__ int cur[MAXNB];
    const int blk = blockIdx.x;
    for (int i = threadIdx.x; i < nb; i += 256) cur[i] = base[i] + C_T[i * nblk + blk];
    __syncthreads();
    const int e0 = blk * EPB;
    const int e1 = min(e0 + EPB, n_edges);
    for (int i = e0 + threadIdx.x; i < e1; i += 256) {
        int d = dst[i];
        int p = atomicAdd(&cur[d >> NB_SHIFT], 1);
        sorted[p] = make_int2(src[i], d);
    }
}

// Pass C: per-bucket counting sort in LDS -> rowptr, col, inv_deg.
__global__ __launch_bounds__(256) void passC_build(const int2* __restrict__ sorted, const int* __restrict__ base,
                                                   int* __restrict__ rowptr, int* __restrict__ col,
                                                   float* __restrict__ invd, int n) {
    __shared__ int degl[128];
    __shared__ int s[256];
    __shared__ int curl[128];
    const int b = blockIdx.x, t = threadIdx.x;
    const int node0 = b << NB_SHIFT;
    const int nn = min(128, n - node0);
    const int e0 = base[b], e1 = base[b + 1];
    if (t < 128) degl[t] = 0;
    __syncthreads();
    for (int i = e0 + t; i < e1; i += 256)
        atomicAdd(&degl[sorted[i].y - node0], 1);
    __syncthreads();
    int d = (t < 128) ? degl[t] : 0;
    s[t] = d; __syncthreads();
    for (int off = 1; off < 128; off <<= 1) {
        int x = (t >= off) ? s[t - off] : 0;
        __syncthreads();
        s[t] += x;
        __syncthreads();
    }
    if (t < 128) {
        int excl = s[t] - d;
        curl[t] = excl;
        if (t < nn) {
            rowptr[node0 + t] = e0 + excl;
            invd[node0 + t] = 1.0f / (float)(d > 0 ? d : 1);
        }
    }
    __syncthreads();
    for (int i = e0 + t; i < e1; i += 256) {
        int2 ed = sorted[i];
        int p = atomicAdd(&curl[ed.y - node0], 1);
        col[e0 + p] = ed.x;
    }
}

// ---- type helpers ----
__device__ inline float4 load4(const float* p) { return *(const float4*)p; }
__device__ inline float4 load4(const __half* p) {
    __half2 a = *(const __half2*)p;
    __half2 b = *(const __half2*)(p + 2);
    float2 fa = __half22float2(a), fb = __half22float2(b);
    return make_float4(fa.x, fa.y, fb.x, fb.y);
}
__device__ inline void store4(float* p, float x0, float x1, float x2, float x3) {
    *(float4*)p = make_float4(x0, x1, x2, x3);
}
__device__ inline void store4(__half* p, float x0, float x1, float x2, float x3) {
    union { __half h[4]; int2 i2; } u;
    u.h[0] = __float2half(x0); u.h[1] = __float2half(x1);
    u.h[2] = __float2half(x2); u.h[3] = __float2half(x3);
    *(int2*)p = u.i2;
}

// Gather-aggregate, MLP-optimized: one node per wave; lane = (edge_slot, feat_quad).
// Each lane gathers 8B (4 fp16); EPW = 64/(FEATS/4) edges in flight per issue.
// EPI: 0 = plain sum; 1 = relu(sum*inv_deg + bias); 2 = sum*inv_deg + bias.
template <int FEATS, int EPI, typename OutT>
__global__ __launch_bounds__(256) void agg_kernel(const __half* __restrict__ X, const int* __restrict__ col,
                                                  const int* __restrict__ rowptr,
                                                  const float* __restrict__ inv_deg,
                                                  const float* __restrict__ bias,
                                                  OutT* __restrict__ out, int n) {
    constexpr int LPE = FEATS / 4;   // lanes per edge (16 or 8)
    constexpr int EPW = 64 / LPE;    // edges per wave-issue (4 or 8)
    const int node = blockIdx.x * 4 + (threadIdx.x >> 6);
    if (node >= n) return;
    const int lane = threadIdx.x & 63;
    const int eg = lane / LPE;       // edge slot within wave
    const int fl = lane % LPE;       // feature-quad index
    const int s = rowptr[node], e = rowptr[node + 1];

    float ax = 0.f, ay = 0.f, az = 0.f, aw = 0.f;
#pragma unroll 2
    for (int i = s; i < e; i += EPW) {
        int idx = i + eg;
        if (idx < e) {
            int c = col[idx];
            const __half* p = X + (size_t)c * FEATS + fl * 4;
            __half2 h01 = *(const __half2*)p;
            __half2 h23 = *(const __half2*)(p + 2);
            float2 f01 = __half22float2(h01);
            float2 f23 = __half22float2(h23);
            ax += f01.x; ay += f01.y; az += f23.x; aw += f23.y;
        }
    }
    // fold edge slots: lanes l, l+LPE, l+2*LPE, ... hold same feature quad
#pragma unroll
    for (int m = LPE; m < 64; m <<= 1) {
        ax += __shfl_xor(ax, m);
        ay += __shfl_xor(ay, m);
        az += __shfl_xor(az, m);
        aw += __shfl_xor(aw, m);
    }
    if (eg == 0) {
        if (EPI != 0) {
            float sc = inv_deg[node];
            ax = ax * sc + bias[fl * 4 + 0];
            ay = ay * sc + bias[fl * 4 + 1];
            az = az * sc + bias[fl * 4 + 2];
            aw = aw * sc + bias[fl * 4 + 3];
            if (EPI == 1) {
                ax = fmaxf(ax, 0.f); ay = fmaxf(ay, 0.f);
                az = fmaxf(az, 0.f); aw = fmaxf(aw, 0.f);
            }
        }
        store4(&out[(size_t)node * FEATS + fl * 4], ax, ay, az, aw);
    }
}

// Skinny f32 GEMM: out[nrows x NOUT] = A[nrows x K] @ Wm[K x NOUT] (+ epilogue).
// A may be f32 or fp16 (converted at LDS stage); math f32.
// EPI: 0 = plain; 1 = relu(x*inv_deg[row] + bias[col]).
template <int K, int NOUT, int EPI, typename InT, typename OutT>
__global__ __launch_bounds__(256) void gemm_kernel(const InT* __restrict__ A, const float* __restrict__ Wm,
                                                   const float* __restrict__ bias,
                                                   const float* __restrict__ inv_deg,
                                                   OutT* __restrict__ out, int nrows) {
    constexpr int BM = 64, BK = 64, NCH = K / BK;
    constexpr int PAD = 68;               // bank-pad: keeps per-k row reads on 2 banks
    __shared__ float As[BM][PAD];
    __shared__ float Ws[BK][NOUT];
    const int t = threadIdx.x;
    constexpr int CG = NOUT / 4;          // col groups (float4 of cols per thread)
    constexpr int RPT = BM / (256 / CG);  // rows per thread
    const int cg = t % CG, rg = t / CG;
    const int row0 = blockIdx.x * BM;

    float acc[RPT][4] = {};

    for (int ch = 0; ch < NCH; ++ch) {
#pragma unroll
        for (int l = 0; l < 4; ++l) {
            int fid = t + l * 256;               // 0..1023 4-elem slots
            int r = fid / (BK / 4);
            int c4 = fid % (BK / 4);
            int grow = row0 + r;
            int gr = grow < nrows ? grow : 0;    // safe row for tail block
            float4 v = load4(&A[(size_t)gr * K + ch * BK + c4 * 4]);
            *(float4*)&As[r][c4 * 4] = v;
        }
#pragma unroll
        for (int l = 0; l < (BK * NOUT / 4) / 256; ++l) {
            int fid = t + l * 256;
            int r = fid / (NOUT / 4);
            int c4 = fid % (NOUT / 4);
            float4 v = *(const float4*)&Wm[(size_t)(ch * BK + r) * NOUT + c4 * 4];
            *(float4*)&Ws[r][c4 * 4] = v;
        }
        __syncthreads();
#pragma unroll 8
        for (int k = 0; k < BK; ++k) {
            float4 w = *(float4*)&Ws[k][cg * 4];
#pragma unroll
            for (int i = 0; i < RPT; ++i) {
                float a = As[rg * RPT + i][k];
                acc[i][0] += a * w.x;
                acc[i][1] += a * w.y;
                acc[i][2] += a * w.z;
                acc[i][3] += a * w.w;
            }
        }
        __syncthreads();
    }

#pragma unroll
    for (int i = 0; i < RPT; ++i) {
        int r = row0 + rg * RPT + i;
        if (r < nrows) {
            float x0 = acc[i][0], x1 = acc[i][1], x2 = acc[i][2], x3 = acc[i][3];
            if (EPI == 1) {
                float sc = inv_deg[r];
                x0 = fmaxf(x0 * sc + bias[cg * 4 + 0], 0.f);
                x1 = fmaxf(x1 * sc + bias[cg * 4 + 1], 0.f);
                x2 = fmaxf(x2 * sc + bias[cg * 4 + 2], 0.f);
                x3 = fmaxf(x3 * sc + bias[cg * 4 + 3], 0.f);
            }
            store4(&out[(size_t)r * NOUT + cg * 4], x0, x1, x2, x3);
        }
    }
}

extern "C" void kernel_launch(void* const* d_in, const int* in_sizes, int n_in,
                              void* d_out, int out_size, void* d_ws, size_t ws_size,
                              hipStream_t stream) {
    const float* feat = (const float*)d_in[0];
    const float* W0   = (const float*)d_in[1];
    const float* b0   = (const float*)d_in[2];
    const float* W1   = (const float*)d_in[3];
    const float* b1   = (const float*)d_in[4];
    const float* W2   = (const float*)d_in[5];
    const float* b2   = (const float*)d_in[6];
    const int*   src  = (const int*)d_in[7];
    const int*   dstv = (const int*)d_in[8];

    const int n = in_sizes[0] / 256;   // 100000
    const int e = in_sizes[7];         // 1600000

    const int nb   = (n + 127) >> NB_SHIFT;        // 782 buckets
    const int nblk = (e + EPB - 1) / EPB;          // 196 blocks

    // Workspace carve-up (256B aligned).
    char* base_p = (char*)d_ws;
    size_t off = 0;
    auto alloc = [&](size_t bytes) -> char* {
        char* p = base_p + off;
        off += (bytes + 255) & ~(size_t)255;
        return p;
    };
    float*  invd   = (float*)alloc((size_t)n * 4);
    int*    rowptr = (int*)alloc((size_t)(n + 1) * 4);
    int*    bbase  = (int*)alloc((size_t)(MAXNB + 1) * 4);
    int*    totals = (int*)alloc((size_t)MAXNB * 4);
    int*    col    = (int*)alloc((size_t)e * 4);          // C_T aliases col
    __half* bufH1  = (__half*)alloc((size_t)n * 64 * 2);  // H, later X2
    __half* bufH2  = (__half*)alloc((size_t)n * 64 * 2);  // X1, later H2
    float*  bufF1  = (float*)alloc((size_t)n * 64 * 4);   // sorted aliases; later A2
    (void)ws_size;

    int*  C_T    = col;            // nb*nblk ints (613KB) — dead before col is written
    int2* sorted = (int2*)bufF1;   // e*8 B (12.8MB) — dead before A2 is written

    // --- CSR build (bucketed sort, no global atomics) ---
    passA_hist   <<<nblk, 256, 0, stream>>>(dstv, C_T, nb, nblk, e);
    bucket_prefix<<<nb,   256, 0, stream>>>(C_T, totals, nblk);
    scan_base    <<<1,    256, 0, stream>>>(totals, bbase, rowptr, nb, n, e);
    passB_scatter<<<nblk, 256, 0, stream>>>(src, dstv, C_T, bbase, sorted, nb, nblk, e);
    passC_build  <<<nb,   256, 0, stream>>>(sorted, bbase, rowptr, col, invd, n);

    const int gemm_blocks = (n + 63) / 64;
    const int agg_blocks  = (n + 3) / 4;   // one wave per node, 4 waves/block

    // --- Layer 0: H = feat@W0 (f32->h) ; X1 = relu(agg(H)*inv + b0) (h) ---
    gemm_kernel<256, 64, 0, float, __half><<<gemm_blocks, 256, 0, stream>>>(feat, W0, nullptr, nullptr, bufH1, n);
    agg_kernel<64, 1, __half><<<agg_blocks, 256, 0, stream>>>(bufH1, col, rowptr, invd, b0, bufH2, n);

    // --- Layer 1: A2 = agg(X1) (f32) ; X2 = relu((A2@W1)*inv + b1) (h) ---
    agg_kernel<64, 0, float><<<agg_blocks, 256, 0, stream>>>(bufH2, col, rowptr, nullptr, nullptr, bufF1, n);
    gemm_kernel<64, 64, 1, float, __half><<<gemm_blocks, 256, 0, stream>>>(bufF1, W1, b1, invd, bufH1, n);

    // --- Layer 2: H2 = X2@W2 (h->h) ; out = agg(H2)*inv + b2 (f32) ---
    gemm_kernel<64, 32, 0, __half, __half><<<gemm_blocks, 256, 0, stream>>>(bufH1, W2, nullptr, nullptr, bufH2, n);
    agg_kernel<32, 2, float><<<agg_blocks, 256, 0, stream>>>(bufH2, col, rowptr, invd, b2, (float*)d_out, n);
}

// Round 5
// 249.925 us; speedup vs baseline: 1.8885x; 1.1880x over previous
//
#include <hip/hip_runtime.h>
#include <hip/hip_bf16.h>
#include <hip/hip_fp16.h>

// GCN: 3 layers over fixed graph (N=100000 nodes, E=1600000 edges).
// CSR build via bucketed sort (packed 4B payload, LDS cursors only).
// Gather aggs: branchless software-pipelined inner loop (col prefetch).
// Layers 1+2 GEMMs fused (X2 kept in LDS). fp16 everywhere off-chip
// except final output; all accumulation f32.

constexpr int NB_SHIFT = 7;          // 128 nodes per bucket
constexpr int EPB = 8192;            // edges per block in pass A/B
constexpr int MAXNB = 800;           // >= ceil(100000/128)=782

// Pass A: per-block LDS histogram over buckets -> C_T[bucket][block] counts.
__global__ __launch_bounds__(256) void passA_hist(const int* __restrict__ dst, int* __restrict__ C_T,
                                                  int nb, int nblk, int n_edges) {
    __shared__ int h[MAXNB];
    for (int i = threadIdx.x; i < nb; i += 256) h[i] = 0;
    __syncthreads();
    const int e0 = blockIdx.x * EPB;
    const int e1 = min(e0 + EPB, n_edges);
    for (int i = e0 + threadIdx.x; i < e1; i += 256)
        atomicAdd(&h[dst[i] >> NB_SHIFT], 1);
    __syncthreads();
    for (int i = threadIdx.x; i < nb; i += 256)
        C_T[i * nblk + blockIdx.x] = h[i];
}

// Per-bucket exclusive scan across blocks (in place); row totals out.
__global__ __launch_bounds__(256) void bucket_prefix(int* __restrict__ C_T, int* __restrict__ totals,
                                                     int nblk) {
    __shared__ int s[256];
    const int b = blockIdx.x, t = threadIdx.x;
    int v = (t < nblk) ? C_T[b * nblk + t] : 0;
    s[t] = v; __syncthreads();
    for (int off = 1; off < 256; off <<= 1) {
        int x = (t >= off) ? s[t - off] : 0;
        __syncthreads();
        s[t] += x;
        __syncthreads();
    }
    if (t < nblk) C_T[b * nblk + t] = s[t] - v;
    if (t == 255) totals[b] = s[255];
}

// Exclusive scan of bucket totals -> base[nb+1]; also rowptr[n]=E.
__global__ __launch_bounds__(256) void scan_base(const int* __restrict__ totals, int* __restrict__ base_out,
                                                 int* __restrict__ rowptr, int nb, int n, int n_edges) {
    __shared__ int s[256];
    const int t = threadIdx.x;
    int v[4]; int ts = 0;
#pragma unroll
    for (int j = 0; j < 4; ++j) { int i = t * 4 + j; v[j] = (i < nb) ? totals[i] : 0; ts += v[j]; }
    s[t] = ts; __syncthreads();
    for (int off = 1; off < 256; off <<= 1) {
        int x = (t >= off) ? s[t - off] : 0;
        __syncthreads();
        s[t] += x;
        __syncthreads();
    }
    int run = s[t] - ts;
#pragma unroll
    for (int j = 0; j < 4; ++j) { int i = t * 4 + j; if (i < nb) base_out[i] = run; run += v[j]; }
    if (t == 255) base_out[nb] = s[255];
    if (t == 0) rowptr[n] = n_edges;
}

// Pass B: scatter packed (ldst<<17)|src into bucket order using LDS cursors.
__global__ __launch_bounds__(256) void passB_scatter(const int* __restrict__ src, const int* __restrict__ dst,
                                                     const int* __restrict__ C_T, const int* __restrict__ base,
                                                     int* __restrict__ sorted_pk, int nb, int nblk, int n_edges) {
    __shared__ int cur[MAXNB];
    const int blk = blockIdx.x;
    for (int i = threadIdx.x; i < nb; i += 256) cur[i] = base[i] + C_T[i * nblk + blk];
    __syncthreads();
    const int e0 = blk * EPB;
    const int e1 = min(e0 + EPB, n_edges);
    for (int i = e0 + threadIdx.x; i < e1; i += 256) {
        int d = dst[i];
        int p = atomicAdd(&cur[d >> NB_SHIFT], 1);
        sorted_pk[p] = ((d & 127) << 17) | src[i];
    }
}

// Pass C: per-bucket counting sort in LDS -> rowptr, col, inv_deg.
__global__ __launch_bounds__(256) void passC_build(const int* __restrict__ sorted_pk, const int* __restrict__ base,
                                                   int* __restrict__ rowptr, int* __restrict__ col,
                                                   float* __restrict__ invd, int n) {
    __shared__ int degl[128];
    __shared__ int s[256];
    __shared__ int curl[128];
    const int b = blockIdx.x, t = threadIdx.x;
    const int node0 = b << NB_SHIFT;
    const int nn = min(128, n - node0);
    const int e0 = base[b], e1 = base[b + 1];
    if (t < 128) degl[t] = 0;
    __syncthreads();
    for (int i = e0 + t; i < e1; i += 256)
        atomicAdd(&degl[sorted_pk[i] >> 17], 1);
    __syncthreads();
    int d = (t < 128) ? degl[t] : 0;
    s[t] = d; __syncthreads();
    for (int off = 1; off < 128; off <<= 1) {
        int x = (t >= off) ? s[t - off] : 0;
        __syncthreads();
        s[t] += x;
        __syncthreads();
    }
    if (t < 128) {
        int excl = s[t] - d;
        curl[t] = excl;
        if (t < nn) {
            rowptr[node0 + t] = e0 + excl;
            invd[node0 + t] = 1.0f / (float)(d > 0 ? d : 1);
        }
    }
    __syncthreads();
    for (int i = e0 + t; i < e1; i += 256) {
        int pk = sorted_pk[i];
        int p = atomicAdd(&curl[pk >> 17], 1);
        col[e0 + p] = pk & 0x1FFFF;
    }
}

// ---- type helpers ----
__device__ inline float4 load4(const float* p) { return *(const float4*)p; }
__device__ inline float4 load4(const __half* p) {
    __half2 a = *(const __half2*)p;
    __half2 b = *(const __half2*)(p + 2);
    float2 fa = __half22float2(a), fb = __half22float2(b);
    return make_float4(fa.x, fa.y, fb.x, fb.y);
}
__device__ inline void store4(float* p, float x0, float x1, float x2, float x3) {
    *(float4*)p = make_float4(x0, x1, x2, x3);
}
__device__ inline void store4(__half* p, float x0, float x1, float x2, float x3) {
    union { __half h[4]; int2 i2; } u;
    u.h[0] = __float2half(x0); u.h[1] = __float2half(x1);
    u.h[2] = __float2half(x2); u.h[3] = __float2half(x3);
    *(int2*)p = u.i2;
}

// Gather-aggregate: one node per wave; lane = (edge_slot, feat_quad).
// Branchless pipelined main loop: col for batch b+1 prefetched (clamped
// address, no branch) while batch b's rows are gathered.
// EPI: 0 = plain sum; 1 = relu(sum*inv_deg + bias); 2 = sum*inv_deg + bias.
template <int FEATS, int EPI, typename OutT>
__global__ __launch_bounds__(256) void agg_kernel(const __half* __restrict__ X, const int* __restrict__ col,
                                                  const int* __restrict__ rowptr,
                                                  const float* __restrict__ inv_deg,
                                                  const float* __restrict__ bias,
                                                  OutT* __restrict__ out, int n) {
    constexpr int LPE = FEATS / 4;   // lanes per edge (16 or 8)
    constexpr int EPW = 64 / LPE;    // edges per wave-issue (4 or 8)
    const int node = blockIdx.x * 4 + (threadIdx.x >> 6);
    if (node >= n) return;
    const int lane = threadIdx.x & 63;
    const int eg = lane / LPE;       // edge slot within wave
    const int fl = lane % LPE;       // feature-quad index
    const int s = rowptr[node], e = rowptr[node + 1];

    float ax = 0.f, ay = 0.f, az = 0.f, aw = 0.f;
    if (e > s) {
        int i = s + eg;
        const int nfull = (e - s) / EPW;
        int cc = col[min(i, e - 1)];
#pragma unroll 2
        for (int b = 0; b < nfull; ++b) {
            int cn = col[min(i + EPW, e - 1)];     // prefetch next batch (clamped, branch-free)
            const __half* p = X + (size_t)cc * FEATS + fl * 4;
            float2 f01 = __half22float2(*(const __half2*)p);
            float2 f23 = __half22float2(*(const __half2*)(p + 2));
            ax += f01.x; ay += f01.y; az += f23.x; aw += f23.y;
            cc = cn; i += EPW;
        }
        if (i < e) {                               // masked tail batch
            const __half* p = X + (size_t)cc * FEATS + fl * 4;
            float2 f01 = __half22float2(*(const __half2*)p);
            float2 f23 = __half22float2(*(const __half2*)(p + 2));
            ax += f01.x; ay += f01.y; az += f23.x; aw += f23.y;
        }
    }
    // fold edge slots: lanes l, l+LPE, ... hold the same feature quad
#pragma unroll
    for (int m = LPE; m < 64; m <<= 1) {
        ax += __shfl_xor(ax, m);
        ay += __shfl_xor(ay, m);
        az += __shfl_xor(az, m);
        aw += __shfl_xor(aw, m);
    }
    if (eg == 0) {
        if (EPI != 0) {
            float sc = inv_deg[node];
            ax = ax * sc + bias[fl * 4 + 0];
            ay = ay * sc + bias[fl * 4 + 1];
            az = az * sc + bias[fl * 4 + 2];
            aw = aw * sc + bias[fl * 4 + 3];
            if (EPI == 1) {
                ax = fmaxf(ax, 0.f); ay = fmaxf(ay, 0.f);
                az = fmaxf(az, 0.f); aw = fmaxf(aw, 0.f);
            }
        }
        store4(&out[(size_t)node * FEATS + fl * 4], ax, ay, az, aw);
    }
}

// Skinny f32 GEMM (layer 0): out = A[nrows x K] @ Wm[K x NOUT], fp16 out.
template <int K, int NOUT, typename InT, typename OutT>
__global__ __launch_bounds__(256) void gemm_kernel(const InT* __restrict__ A, const float* __restrict__ Wm,
                                                   OutT* __restrict__ out, int nrows) {
    constexpr int BM = 64, BK = 64, NCH = K / BK;
    constexpr int PAD = 68;               // bank-pad
    __shared__ float As[BM][PAD];
    __shared__ float Ws[BK][NOUT];
    const int t = threadIdx.x;
    constexpr int CG = NOUT / 4;
    constexpr int RPT = BM / (256 / CG);
    const int cg = t % CG, rg = t / CG;
    const int row0 = blockIdx.x * BM;

    float acc[RPT][4] = {};

    for (int ch = 0; ch < NCH; ++ch) {
#pragma unroll
        for (int l = 0; l < 4; ++l) {
            int fid = t + l * 256;
            int r = fid / (BK / 4);
            int c4 = fid % (BK / 4);
            int grow = row0 + r;
            int gr = grow < nrows ? grow : 0;
            float4 v = load4(&A[(size_t)gr * K + ch * BK + c4 * 4]);
            *(float4*)&As[r][c4 * 4] = v;
        }
#pragma unroll
        for (int l = 0; l < (BK * NOUT / 4) / 256; ++l) {
            int fid = t + l * 256;
            int r = fid / (NOUT / 4);
            int c4 = fid % (NOUT / 4);
            float4 v = *(const float4*)&Wm[(size_t)(ch * BK + r) * NOUT + c4 * 4];
            *(float4*)&Ws[r][c4 * 4] = v;
        }
        __syncthreads();
#pragma unroll 8
        for (int k = 0; k < BK; ++k) {
            float4 w = *(float4*)&Ws[k][cg * 4];
#pragma unroll
            for (int i = 0; i < RPT; ++i) {
                float a = As[rg * RPT + i][k];
                acc[i][0] += a * w.x;
                acc[i][1] += a * w.y;
                acc[i][2] += a * w.z;
                acc[i][3] += a * w.w;
            }
        }
        __syncthreads();
    }

#pragma unroll
    for (int i = 0; i < RPT; ++i) {
        int r = row0 + rg * RPT + i;
        if (r < nrows)
            store4(&out[(size_t)r * NOUT + cg * 4], acc[i][0], acc[i][1], acc[i][2], acc[i][3]);
    }
}

// Fused layers 1+2 GEMM: X2 = relu((A2@W1)*inv+b1) kept in LDS; H2 = X2@W2 out (fp16).
__global__ __launch_bounds__(256) void gemm12_kernel(const __half* __restrict__ A2, const float* __restrict__ W1,
                                                     const float* __restrict__ b1, const float* __restrict__ W2,
                                                     const float* __restrict__ inv_deg,
                                                     __half* __restrict__ out, int nrows) {
    __shared__ float As[64][68];     // A2 tile; reused as X2 tile in phase 2
    __shared__ float W1s[64][64];
    __shared__ float W2s[64][32];
    const int t = threadIdx.x;
    const int row0 = blockIdx.x * 64;
    const int cg = t % 16, rg = t / 16;   // phase 1: 4 cols x 4 rows per thread

    // Stage A2 (fp16 -> f32) and W1, W2.
#pragma unroll
    for (int l = 0; l < 4; ++l) {
        int fid = t + l * 256;
        int r = fid / 16, c4 = fid % 16;
        int grow = row0 + r;
        int gr = grow < nrows ? grow : 0;
        float4 v = load4(&A2[(size_t)gr * 64 + c4 * 4]);
        *(float4*)&As[r][c4 * 4] = v;
    }
#pragma unroll
    for (int l = 0; l < 4; ++l) {
        int fid = t + l * 256;
        int r = fid / 16, c4 = fid % 16;
        *(float4*)&W1s[r][c4 * 4] = *(const float4*)&W1[(size_t)r * 64 + c4 * 4];
    }
#pragma unroll
    for (int l = 0; l < 2; ++l) {
        int fid = t + l * 256;
        int r = fid / 8, c4 = fid % 8;
        *(float4*)&W2s[r][c4 * 4] = *(const float4*)&W2[(size_t)r * 32 + c4 * 4];
    }
    __syncthreads();

    // Phase 1: acc = A2 @ W1
    float acc[4][4] = {};
#pragma unroll 8
    for (int k = 0; k < 64; ++k) {
        float4 w = *(float4*)&W1s[k][cg * 4];
#pragma unroll
        for (int i = 0; i < 4; ++i) {
            float a = As[rg * 4 + i][k];
            acc[i][0] += a * w.x;
            acc[i][1] += a * w.y;
            acc[i][2] += a * w.z;
            acc[i][3] += a * w.w;
        }
    }
    __syncthreads();   // done reading As

    // X2 = relu(acc*inv + b1) -> back into As (as X2 tile)
#pragma unroll
    for (int i = 0; i < 4; ++i) {
        int r = row0 + rg * 4 + i;
        float sc = (r < nrows) ? inv_deg[r] : 0.f;
        float x0 = fmaxf(acc[i][0] * sc + b1[cg * 4 + 0], 0.f);
        float x1 = fmaxf(acc[i][1] * sc + b1[cg * 4 + 1], 0.f);
        float x2 = fmaxf(acc[i][2] * sc + b1[cg * 4 + 2], 0.f);
        float x3 = fmaxf(acc[i][3] * sc + b1[cg * 4 + 3], 0.f);
        *(float4*)&As[rg * 4 + i][cg * 4] = make_float4(x0, x1, x2, x3);
    }
    __syncthreads();

    // Phase 2: H2 = X2 @ W2 (64x64 @ 64x32), 2 rows x 4 cols per thread
    const int cg2 = t % 8, rg2 = t / 8;
    float acc2[2][4] = {};
#pragma unroll 8
    for (int k = 0; k < 64; ++k) {
        float4 w = *(float4*)&W2s[k][cg2 * 4];
#pragma unroll
        for (int i = 0; i < 2; ++i) {
            float a = As[rg2 * 2 + i][k];
            acc2[i][0] += a * w.x;
            acc2[i][1] += a * w.y;
            acc2[i][2] += a * w.z;
            acc2[i][3] += a * w.w;
        }
    }
#pragma unroll
    for (int i = 0; i < 2; ++i) {
        int r = row0 + rg2 * 2 + i;
        if (r < nrows)
            store4(&out[(size_t)r * 32 + cg2 * 4], acc2[i][0], acc2[i][1], acc2[i][2], acc2[i][3]);
    }
}

extern "C" void kernel_launch(void* const* d_in, const int* in_sizes, int n_in,
                              void* d_out, int out_size, void* d_ws, size_t ws_size,
                              hipStream_t stream) {
    const float* feat = (const float*)d_in[0];
    const float* W0   = (const float*)d_in[1];
    const float* b0   = (const float*)d_in[2];
    const float* W1   = (const float*)d_in[3];
    const float* b1   = (const float*)d_in[4];
    const float* W2   = (const float*)d_in[5];
    const float* b2   = (const float*)d_in[6];
    const int*   src  = (const int*)d_in[7];
    const int*   dstv = (const int*)d_in[8];

    const int n = in_sizes[0] / 256;   // 100000
    const int e = in_sizes[7];         // 1600000

    const int nb   = (n + 127) >> NB_SHIFT;        // 782 buckets
    const int nblk = (e + EPB - 1) / EPB;          // 196 blocks

    // Workspace carve-up (256B aligned).
    char* base_p = (char*)d_ws;
    size_t off = 0;
    auto alloc = [&](size_t bytes) -> char* {
        char* p = base_p + off;
        off += (bytes + 255) & ~(size_t)255;
        return p;
    };
    float*  invd   = (float*)alloc((size_t)n * 4);
    int*    rowptr = (int*)alloc((size_t)(n + 1) * 4);
    int*    bbase  = (int*)alloc((size_t)(MAXNB + 1) * 4);
    int*    totals = (int*)alloc((size_t)MAXNB * 4);
    int*    col    = (int*)alloc((size_t)e * 4);          // C_T aliases col
    __half* bufH1  = (__half*)alloc((size_t)n * 64 * 2);  // H; later A2. sorted_pk aliases.
    __half* bufH2  = (__half*)alloc((size_t)n * 64 * 2);  // X1; later H2
    (void)ws_size;

    int* C_T       = col;           // nb*nblk ints (613KB) — dead before col is written
    int* sorted_pk = (int*)bufH1;   // e*4 B (6.4MB) — dead before gemm0 writes bufH1

    // --- CSR build (bucketed sort, no global atomics) ---
    passA_hist   <<<nblk, 256, 0, stream>>>(dstv, C_T, nb, nblk, e);
    bucket_prefix<<<nb,   256, 0, stream>>>(C_T, totals, nblk);
    scan_base    <<<1,    256, 0, stream>>>(totals, bbase, rowptr, nb, n, e);
    passB_scatter<<<nblk, 256, 0, stream>>>(src, dstv, C_T, bbase, sorted_pk, nb, nblk, e);
    passC_build  <<<nb,   256, 0, stream>>>(sorted_pk, bbase, rowptr, col, invd, n);

    const int gemm_blocks = (n + 63) / 64;
    const int agg_blocks  = (n + 3) / 4;   // one wave per node, 4 waves/block

    // --- Layer 0: H = feat@W0 (f32->h) ; X1 = relu(agg(H)*inv + b0) (h) ---
    gemm_kernel<256, 64, float, __half><<<gemm_blocks, 256, 0, stream>>>(feat, W0, bufH1, n);
    agg_kernel<64, 1, __half><<<agg_blocks, 256, 0, stream>>>(bufH1, col, rowptr, invd, b0, bufH2, n);

    // --- Layer 1: A2 = agg(X1) (h) ; fused: X2 = relu((A2@W1)*inv+b1); H2 = X2@W2 (h) ---
    agg_kernel<64, 0, __half><<<agg_blocks, 256, 0, stream>>>(bufH2, col, rowptr, nullptr, nullptr, bufH1, n);
    gemm12_kernel<<<gemm_blocks, 256, 0, stream>>>(bufH1, W1, b1, W2, invd, bufH2, n);

    // --- Layer 2: out = agg(H2)*inv + b2 (f32) ---
    agg_kernel<32, 2, float><<<agg_blocks, 256, 0, stream>>>(bufH2, col, rowptr, invd, b2, (float*)d_out, n);
}

// Round 6
// 214.832 us; speedup vs baseline: 2.1970x; 1.1633x over previous
//
#include <hip/hip_runtime.h>
#include <hip/hip_bf16.h>
#include <hip/hip_fp16.h>

// GCN: 3 layers over fixed graph (N=100000 nodes, E=1600000 edges).
// CSR build via bucketed sort (packed 4B payload, LDS cursors only).
// Gather aggs: branchless software-pipelined inner loop (col prefetch).
// Layer-0 GEMM (K=256) on matrix cores: mfma_f32_16x16x32_f16, fp16
// operands, f32 accum. Layers 1+2 GEMMs fused (X2 in LDS), vector f32.

constexpr int NB_SHIFT = 7;          // 128 nodes per bucket
constexpr int EPB = 8192;            // edges per block in pass A/B
constexpr int MAXNB = 800;           // >= ceil(100000/128)=782

using half8  = __attribute__((ext_vector_type(8))) _Float16;
using floatx4 = __attribute__((ext_vector_type(4))) float;

// Pass A: per-block LDS histogram over buckets -> C_T[bucket][block] counts.
__global__ __launch_bounds__(256) void passA_hist(const int* __restrict__ dst, int* __restrict__ C_T,
                                                  int nb, int nblk, int n_edges) {
    __shared__ int h[MAXNB];
    for (int i = threadIdx.x; i < nb; i += 256) h[i] = 0;
    __syncthreads();
    const int e0 = blockIdx.x * EPB;
    const int e1 = min(e0 + EPB, n_edges);
    for (int i = e0 + threadIdx.x; i < e1; i += 256)
        atomicAdd(&h[dst[i] >> NB_SHIFT], 1);
    __syncthreads();
    for (int i = threadIdx.x; i < nb; i += 256)
        C_T[i * nblk + blockIdx.x] = h[i];
}

// Per-bucket exclusive scan across blocks (in place); row totals out.
__global__ __launch_bounds__(256) void bucket_prefix(int* __restrict__ C_T, int* __restrict__ totals,
                                                     int nblk) {
    __shared__ int s[256];
    const int b = blockIdx.x, t = threadIdx.x;
    int v = (t < nblk) ? C_T[b * nblk + t] : 0;
    s[t] = v; __syncthreads();
    for (int off = 1; off < 256; off <<= 1) {
        int x = (t >= off) ? s[t - off] : 0;
        __syncthreads();
        s[t] += x;
        __syncthreads();
    }
    if (t < nblk) C_T[b * nblk + t] = s[t] - v;
    if (t == 255) totals[b] = s[255];
}

// Exclusive scan of bucket totals -> base[nb+1]; also rowptr[n]=E.
__global__ __launch_bounds__(256) void scan_base(const int* __restrict__ totals, int* __restrict__ base_out,
                                                 int* __restrict__ rowptr, int nb, int n, int n_edges) {
    __shared__ int s[256];
    const int t = threadIdx.x;
    int v[4]; int ts = 0;
#pragma unroll
    for (int j = 0; j < 4; ++j) { int i = t * 4 + j; v[j] = (i < nb) ? totals[i] : 0; ts += v[j]; }
    s[t] = ts; __syncthreads();
    for (int off = 1; off < 256; off <<= 1) {
        int x = (t >= off) ? s[t - off] : 0;
        __syncthreads();
        s[t] += x;
        __syncthreads();
    }
    int run = s[t] - ts;
#pragma unroll
    for (int j = 0; j < 4; ++j) { int i = t * 4 + j; if (i < nb) base_out[i] = run; run += v[j]; }
    if (t == 255) base_out[nb] = s[255];
    if (t == 0) rowptr[n] = n_edges;
}

// Pass B: scatter packed (ldst<<17)|src into bucket order using LDS cursors.
__global__ __launch_bounds__(256) void passB_scatter(const int* __restrict__ src, const int* __restrict__ dst,
                                                     const int* __restrict__ C_T, const int* __restrict__ base,
                                                     int* __restrict__ sorted_pk, int nb, int nblk, int n_edges) {
    __shared__ int cur[MAXNB];
    const int blk = blockIdx.x;
    for (int i = threadIdx.x; i < nb; i += 256) cur[i] = base[i] + C_T[i * nblk + blk];
    __syncthreads();
    const int e0 = blk * EPB;
    const int e1 = min(e0 + EPB, n_edges);
    for (int i = e0 + threadIdx.x; i < e1; i += 256) {
        int d = dst[i];
        int p = atomicAdd(&cur[d >> NB_SHIFT], 1);
        sorted_pk[p] = ((d & 127) << 17) | src[i];
    }
}

// Pass C: per-bucket counting sort in LDS -> rowptr, col, inv_deg.
__global__ __launch_bounds__(256) void passC_build(const int* __restrict__ sorted_pk, const int* __restrict__ base,
                                                   int* __restrict__ rowptr, int* __restrict__ col,
                                                   float* __restrict__ invd, int n) {
    __shared__ int degl[128];
    __shared__ int s[256];
    __shared__ int curl[128];
    const int b = blockIdx.x, t = threadIdx.x;
    const int node0 = b << NB_SHIFT;
    const int nn = min(128, n - node0);
    const int e0 = base[b], e1 = base[b + 1];
    if (t < 128) degl[t] = 0;
    __syncthreads();
    for (int i = e0 + t; i < e1; i += 256)
        atomicAdd(&degl[sorted_pk[i] >> 17], 1);
    __syncthreads();
    int d = (t < 128) ? degl[t] : 0;
    s[t] = d; __syncthreads();
    for (int off = 1; off < 128; off <<= 1) {
        int x = (t >= off) ? s[t - off] : 0;
        __syncthreads();
        s[t] += x;
        __syncthreads();
    }
    if (t < 128) {
        int excl = s[t] - d;
        curl[t] = excl;
        if (t < nn) {
            rowptr[node0 + t] = e0 + excl;
            invd[node0 + t] = 1.0f / (float)(d > 0 ? d : 1);
        }
    }
    __syncthreads();
    for (int i = e0 + t; i < e1; i += 256) {
        int pk = sorted_pk[i];
        int p = atomicAdd(&curl[pk >> 17], 1);
        col[e0 + p] = pk & 0x1FFFF;
    }
}

// ---- type helpers ----
__device__ inline float4 load4(const float* p) { return *(const float4*)p; }
__device__ inline float4 load4(const __half* p) {
    __half2 a = *(const __half2*)p;
    __half2 b = *(const __half2*)(p + 2);
    float2 fa = __half22float2(a), fb = __half22float2(b);
    return make_float4(fa.x, fa.y, fb.x, fb.y);
}
__device__ inline void store4(float* p, float x0, float x1, float x2, float x3) {
    *(float4*)p = make_float4(x0, x1, x2, x3);
}
__device__ inline void store4(__half* p, float x0, float x1, float x2, float x3) {
    union { __half h[4]; int2 i2; } u;
    u.h[0] = __float2half(x0); u.h[1] = __float2half(x1);
    u.h[2] = __float2half(x2); u.h[3] = __float2half(x3);
    *(int2*)p = u.i2;
}

// Gather-aggregate: one node per wave; lane = (edge_slot, feat_quad).
// Branchless pipelined main loop: col for batch b+1 prefetched (clamped).
// EPI: 0 = plain sum; 1 = relu(sum*inv_deg + bias); 2 = sum*inv_deg + bias.
template <int FEATS, int EPI, typename OutT>
__global__ __launch_bounds__(256) void agg_kernel(const __half* __restrict__ X, const int* __restrict__ col,
                                                  const int* __restrict__ rowptr,
                                                  const float* __restrict__ inv_deg,
                                                  const float* __restrict__ bias,
                                                  OutT* __restrict__ out, int n) {
    constexpr int LPE = FEATS / 4;   // lanes per edge (16 or 8)
    constexpr int EPW = 64 / LPE;    // edges per wave-issue (4 or 8)
    const int node = blockIdx.x * 4 + (threadIdx.x >> 6);
    if (node >= n) return;
    const int lane = threadIdx.x & 63;
    const int eg = lane / LPE;       // edge slot within wave
    const int fl = lane % LPE;       // feature-quad index
    const int s = rowptr[node], e = rowptr[node + 1];

    float ax = 0.f, ay = 0.f, az = 0.f, aw = 0.f;
    if (e > s) {
        int i = s + eg;
        const int nfull = (e - s) / EPW;
        int cc = col[min(i, e - 1)];
#pragma unroll 2
        for (int b = 0; b < nfull; ++b) {
            int cn = col[min(i + EPW, e - 1)];     // prefetch next batch (clamped, branch-free)
            const __half* p = X + (size_t)cc * FEATS + fl * 4;
            float2 f01 = __half22float2(*(const __half2*)p);
            float2 f23 = __half22float2(*(const __half2*)(p + 2));
            ax += f01.x; ay += f01.y; az += f23.x; aw += f23.y;
            cc = cn; i += EPW;
        }
        if (i < e) {                               // masked tail batch
            const __half* p = X + (size_t)cc * FEATS + fl * 4;
            float2 f01 = __half22float2(*(const __half2*)p);
            float2 f23 = __half22float2(*(const __half2*)(p + 2));
            ax += f01.x; ay += f01.y; az += f23.x; aw += f23.y;
        }
    }
#pragma unroll
    for (int m = LPE; m < 64; m <<= 1) {
        ax += __shfl_xor(ax, m);
        ay += __shfl_xor(ay, m);
        az += __shfl_xor(az, m);
        aw += __shfl_xor(aw, m);
    }
    if (eg == 0) {
        if (EPI != 0) {
            float sc = inv_deg[node];
            ax = ax * sc + bias[fl * 4 + 0];
            ay = ay * sc + bias[fl * 4 + 1];
            az = az * sc + bias[fl * 4 + 2];
            aw = aw * sc + bias[fl * 4 + 3];
            if (EPI == 1) {
                ax = fmaxf(ax, 0.f); ay = fmaxf(ay, 0.f);
                az = fmaxf(az, 0.f); aw = fmaxf(aw, 0.f);
            }
        }
        store4(&out[(size_t)node * FEATS + fl * 4], ax, ay, az, aw);
    }
}

// Transpose+convert W0 [256][64] f32 -> W0t [64][256] fp16.
__global__ __launch_bounds__(256) void cvtW0t(const float* __restrict__ W0, __half* __restrict__ W0t) {
    int o = blockIdx.x * 256 + threadIdx.x;   // 16384 elems
    int c = o >> 8, k = o & 255;
    W0t[o] = __float2half(W0[k * 64 + c]);
}

// Layer-0 GEMM on matrix cores: H[nrows x 64] = feat[nrows x 256] @ W0 (fp16 in, f32 acc).
// 4 waves/block; wave w owns output rows [w*16, w*16+16) x all 64 cols.
// Fragment layout (gfx950 16x16x32): A/B lane l -> row/col = l&15, k0 = (l>>4)*8 (8 contiguous);
// C/D lane l -> col = l&15, row = (l>>4)*4 + reg.
__global__ __launch_bounds__(256) void gemm0_mfma(const float* __restrict__ A, const __half* __restrict__ W0t,
                                                  __half* __restrict__ out, int nrows) {
    constexpr int LDH = 280;   // fp16 pad: 560B row stride = 16B aligned, 12-bank skew (2-way = free)
    __shared__ _Float16 As[64][LDH];
    __shared__ _Float16 Bs[64][LDH];
    const int t = threadIdx.x;
    const int wave = t >> 6, lane = t & 63;
    const int row0 = blockIdx.x * 64;

    // Stage A: 64 rows x 256 cols f32 -> fp16. 4096 float4 slots, 16/thread.
#pragma unroll
    for (int l = 0; l < 16; ++l) {
        int fid = t + l * 256;
        int r = fid >> 6, c4 = fid & 63;
        int grow = row0 + r;
        int gr = grow < nrows ? grow : 0;
        float4 v = *(const float4*)&A[(size_t)gr * 256 + c4 * 4];
        _Float16* p = &As[r][c4 * 4];
        p[0] = (_Float16)v.x; p[1] = (_Float16)v.y;
        p[2] = (_Float16)v.z; p[3] = (_Float16)v.w;
    }
    // Stage B: W0t [64][256] fp16, 2048 8-half chunks, 8/thread.
#pragma unroll
    for (int l = 0; l < 8; ++l) {
        int fid = t + l * 256;
        int r = fid >> 5, c8 = fid & 31;
        *(half8*)&Bs[r][c8 * 8] = *(const half8*)&W0t[r * 256 + c8 * 8];
    }
    __syncthreads();

    const int ar = wave * 16 + (lane & 15);   // A row this lane supplies
    const int kh = (lane >> 4) * 8;           // k sub-offset
    floatx4 acc0 = {0.f, 0.f, 0.f, 0.f}, acc1 = acc0, acc2 = acc0, acc3 = acc0;
#pragma unroll
    for (int ks = 0; ks < 8; ++ks) {
        const int k0 = ks * 32 + kh;
        half8 a = *(half8*)&As[ar][k0];
        half8 b0 = *(half8*)&Bs[ 0 + (lane & 15)][k0];
        half8 b1 = *(half8*)&Bs[16 + (lane & 15)][k0];
        half8 b2 = *(half8*)&Bs[32 + (lane & 15)][k0];
        half8 b3 = *(half8*)&Bs[48 + (lane & 15)][k0];
        acc0 = __builtin_amdgcn_mfma_f32_16x16x32_f16(a, b0, acc0, 0, 0, 0);
        acc1 = __builtin_amdgcn_mfma_f32_16x16x32_f16(a, b1, acc1, 0, 0, 0);
        acc2 = __builtin_amdgcn_mfma_f32_16x16x32_f16(a, b2, acc2, 0, 0, 0);
        acc3 = __builtin_amdgcn_mfma_f32_16x16x32_f16(a, b3, acc3, 0, 0, 0);
    }

    // Epilogue: lane writes col = lane&15 of each col-frag, rows (lane>>4)*4+i.
    const int cc = lane & 15;
    const int rb = wave * 16 + (lane >> 4) * 4;
#pragma unroll
    for (int i = 0; i < 4; ++i) {
        int r = row0 + rb + i;
        if (r < nrows) {
            __half* po = &out[(size_t)r * 64];
            po[ 0 + cc] = __float2half(acc0[i]);
            po[16 + cc] = __float2half(acc1[i]);
            po[32 + cc] = __float2half(acc2[i]);
            po[48 + cc] = __float2half(acc3[i]);
        }
    }
}

// Fused layers 1+2 GEMM: X2 = relu((A2@W1)*inv+b1) kept in LDS; H2 = X2@W2 out (fp16).
__global__ __launch_bounds__(256) void gemm12_kernel(const __half* __restrict__ A2, const float* __restrict__ W1,
                                                     const float* __restrict__ b1, const float* __restrict__ W2,
                                                     const float* __restrict__ inv_deg,
                                                     __half* __restrict__ out, int nrows) {
    __shared__ float As[64][68];     // A2 tile; reused as X2 tile in phase 2
    __shared__ float W1s[64][64];
    __shared__ float W2s[64][32];
    const int t = threadIdx.x;
    const int row0 = blockIdx.x * 64;
    const int cg = t % 16, rg = t / 16;

#pragma unroll
    for (int l = 0; l < 4; ++l) {
        int fid = t + l * 256;
        int r = fid / 16, c4 = fid % 16;
        int grow = row0 + r;
        int gr = grow < nrows ? grow : 0;
        float4 v = load4(&A2[(size_t)gr * 64 + c4 * 4]);
        *(float4*)&As[r][c4 * 4] = v;
    }
#pragma unroll
    for (int l = 0; l < 4; ++l) {
        int fid = t + l * 256;
        int r = fid / 16, c4 = fid % 16;
        *(float4*)&W1s[r][c4 * 4] = *(const float4*)&W1[(size_t)r * 64 + c4 * 4];
    }
#pragma unroll
    for (int l = 0; l < 2; ++l) {
        int fid = t + l * 256;
        int r = fid / 8, c4 = fid % 8;
        *(float4*)&W2s[r][c4 * 4] = *(const float4*)&W2[(size_t)r * 32 + c4 * 4];
    }
    __syncthreads();

    float acc[4][4] = {};
#pragma unroll 8
    for (int k = 0; k < 64; ++k) {
        float4 w = *(float4*)&W1s[k][cg * 4];
#pragma unroll
        for (int i = 0; i < 4; ++i) {
            float a = As[rg * 4 + i][k];
            acc[i][0] += a * w.x;
            acc[i][1] += a * w.y;
            acc[i][2] += a * w.z;
            acc[i][3] += a * w.w;
        }
    }
    __syncthreads();

#pragma unroll
    for (int i = 0; i < 4; ++i) {
        int r = row0 + rg * 4 + i;
        float sc = (r < nrows) ? inv_deg[r] : 0.f;
        float x0 = fmaxf(acc[i][0] * sc + b1[cg * 4 + 0], 0.f);
        float x1 = fmaxf(acc[i][1] * sc + b1[cg * 4 + 1], 0.f);
        float x2 = fmaxf(acc[i][2] * sc + b1[cg * 4 + 2], 0.f);
        float x3 = fmaxf(acc[i][3] * sc + b1[cg * 4 + 3], 0.f);
        *(float4*)&As[rg * 4 + i][cg * 4] = make_float4(x0, x1, x2, x3);
    }
    __syncthreads();

    const int cg2 = t % 8, rg2 = t / 8;
    float acc2[2][4] = {};
#pragma unroll 8
    for (int k = 0; k < 64; ++k) {
        float4 w = *(float4*)&W2s[k][cg2 * 4];
#pragma unroll
        for (int i = 0; i < 2; ++i) {
            float a = As[rg2 * 2 + i][k];
            acc2[i][0] += a * w.x;
            acc2[i][1] += a * w.y;
            acc2[i][2] += a * w.z;
            acc2[i][3] += a * w.w;
        }
    }
#pragma unroll
    for (int i = 0; i < 2; ++i) {
        int r = row0 + rg2 * 2 + i;
        if (r < nrows)
            store4(&out[(size_t)r * 32 + cg2 * 4], acc2[i][0], acc2[i][1], acc2[i][2], acc2[i][3]);
    }
}

extern "C" void kernel_launch(void* const* d_in, const int* in_sizes, int n_in,
                              void* d_out, int out_size, void* d_ws, size_t ws_size,
                              hipStream_t stream) {
    const float* feat = (const float*)d_in[0];
    const float* W0   = (const float*)d_in[1];
    const float* b0   = (const float*)d_in[2];
    const float* W1   = (const float*)d_in[3];
    const float* b1   = (const float*)d_in[4];
    const float* W2   = (const float*)d_in[5];
    const float* b2   = (const float*)d_in[6];
    const int*   src  = (const int*)d_in[7];
    const int*   dstv = (const int*)d_in[8];

    const int n = in_sizes[0] / 256;   // 100000
    const int e = in_sizes[7];         // 1600000

    const int nb   = (n + 127) >> NB_SHIFT;        // 782 buckets
    const int nblk = (e + EPB - 1) / EPB;          // 196 blocks

    // Workspace carve-up (256B aligned).
    char* base_p = (char*)d_ws;
    size_t off = 0;
    auto alloc = [&](size_t bytes) -> char* {
        char* p = base_p + off;
        off += (bytes + 255) & ~(size_t)255;
        return p;
    };
    float*  invd   = (float*)alloc((size_t)n * 4);
    int*    rowptr = (int*)alloc((size_t)(n + 1) * 4);
    int*    bbase  = (int*)alloc((size_t)(MAXNB + 1) * 4);
    int*    totals = (int*)alloc((size_t)MAXNB * 4);
    __half* W0t    = (__half*)alloc((size_t)256 * 64 * 2);
    int*    col    = (int*)alloc((size_t)e * 4);          // C_T aliases col
    __half* bufH1  = (__half*)alloc((size_t)n * 64 * 2);  // H; later A2. sorted_pk aliases.
    __half* bufH2  = (__half*)alloc((size_t)n * 64 * 2);  // X1; later H2
    (void)ws_size;

    int* C_T       = col;           // nb*nblk ints (613KB) — dead before col is written
    int* sorted_pk = (int*)bufH1;   // e*4 B (6.4MB) — dead before gemm0 writes bufH1

    // --- CSR build (bucketed sort, no global atomics) ---
    passA_hist   <<<nblk, 256, 0, stream>>>(dstv, C_T, nb, nblk, e);
    bucket_prefix<<<nb,   256, 0, stream>>>(C_T, totals, nblk);
    scan_base    <<<1,    256, 0, stream>>>(totals, bbase, rowptr, nb, n, e);
    passB_scatter<<<nblk, 256, 0, stream>>>(src, dstv, C_T, bbase, sorted_pk, nb, nblk, e);
    passC_build  <<<nb,   256, 0, stream>>>(sorted_pk, bbase, rowptr, col, invd, n);
    cvtW0t       <<<64,   256, 0, stream>>>(W0, W0t);

    const int gemm_blocks = (n + 63) / 64;
    const int agg_blocks  = (n + 3) / 4;   // one wave per node, 4 waves/block

    // --- Layer 0: H = feat@W0 (MFMA fp16) ; X1 = relu(agg(H)*inv + b0) (h) ---
    gemm0_mfma<<<gemm_blocks, 256, 0, stream>>>(feat, W0t, bufH1, n);
    agg_kernel<64, 1, __half><<<agg_blocks, 256, 0, stream>>>(bufH1, col, rowptr, invd, b0, bufH2, n);

    // --- Layer 1: A2 = agg(X1) (h) ; fused: X2 = relu((A2@W1)*inv+b1); H2 = X2@W2 (h) ---
    agg_kernel<64, 0, __half><<<agg_blocks, 256, 0, stream>>>(bufH2, col, rowptr, nullptr, nullptr, bufH1, n);
    gemm12_kernel<<<gemm_blocks, 256, 0, stream>>>(bufH1, W1, b1, W2, invd, bufH2, n);

    // --- Layer 2: out = agg(H2)*inv + b2 (f32) ---
    agg_kernel<32, 2, float><<<agg_blocks, 256, 0, stream>>>(bufH2, col, rowptr, invd, b2, (float*)d_out, n);
}